// Round 10
// baseline (151.875 us; speedup 1.0000x reference)
//
#include <hip/hip_runtime.h>
#include <math.h>

namespace {
constexpr int Hh = 128, Ww = 128;
constexpr int NDCAP = 48;     // max stencil offsets per radius
constexpr int UROW  = 56;     // uoff row stride in ints

using short8 = __attribute__((ext_vector_type(8))) short;
using f32x4  = __attribute__((ext_vector_type(4))) float;

__device__ __forceinline__ unsigned short f2bf(float f) {
    union { float f; unsigned int u; } v; v.f = f;
    unsigned int u = v.u;
    unsigned int r = (u + 0x7FFFu + ((u >> 16) & 1u)) >> 16;   // RNE
    return (unsigned short)r;
}
__device__ __forceinline__ float bflo(unsigned int u) {
    union { unsigned int u; float f; } v; v.u = u << 16; return v.f;
}
__device__ __forceinline__ float bfhi(unsigned int u) {
    union { unsigned int u; float f; } v; v.u = u & 0xffff0000u; return v.f;
}

union U8 { unsigned int d[4]; short8 s; };

// workspace layout (bytes)
constexpr size_t XBF_OFF  = 0;                                  // 4*16384*64 bf16 = 8388608
constexpr size_t W1P_OFF  = 8388608;                            // 484 chunks * 4096 B
constexpr size_t W2P_OFF  = W1P_OFF + (size_t)484 * 4096;       // 40960 B
constexpr size_t META_OFF = W2P_OFF + 40960;                    // 64 B (16 ints)
constexpr size_t UOFF_OFF = META_OFF + 64;                      // 5*56*4 = 1120 -> 1152
constexpr size_t WVEC_OFF = UOFF_OFF + 1152;                    // 5*48*8*4 = 7680
constexpr size_t WS_NEED  = WVEC_OFF + 7680;
}

// ---------------- k0: stencil table builder (parallel, deterministic) ----------------
__global__ void rrf_table(int* __restrict__ meta, int* __restrict__ uoff,
                          float* __restrict__ wvec)
{
    __shared__ float grid[5][81][8];
    __shared__ unsigned char keep[5][81];
    __shared__ short dofs[5][81];
    __shared__ int nds[5];

    const int t = threadIdx.x;                // 512 threads
    for (int i = t; i < 5 * 81 * 8; i += 512) ((float*)grid)[i] = 0.f;
    for (int i = t; i < 5 * UROW; i += 512) uoff[i] = 0;
    __syncthreads();

    if (t < 40) {                             // one thread per (r,p) tap set
        int r = t >> 3, p = t & 7;
        float ang = (float)p * 0.78539818525314331f;     // f32(2pi)/8
        float si = (float)sin((double)ang);
        float co = (float)cos((double)ang);
        float di = (float)r * si;
        float dj = (float)r * co;
        float y0f = floorf(di), x0f = floorf(dj);
        float wy = di - y0f, wx = dj - x0f;
        int y0 = (int)y0f, x0 = (int)x0f;
        float tw[4] = {(1.f - wy) * (1.f - wx), (1.f - wy) * wx,
                       wy * (1.f - wx), wy * wx};
        int ty[4] = {y0, y0, y0 + 1, y0 + 1};
        int tx[4] = {x0, x0 + 1, x0, x0 + 1};
        #pragma unroll
        for (int q = 0; q < 4; ++q) {
            if (fabsf(tw[q]) < 1e-6f) continue;
            grid[r][(ty[q] + 4) * 9 + (tx[q] + 4)][p] = tw[q];
        }
    }
    __syncthreads();

    if (t < 405) {
        int r = t / 81, ci = t - r * 81;
        float mx = 0.f;
        #pragma unroll
        for (int p = 0; p < 8; ++p) mx = fmaxf(mx, fabsf(grid[r][ci][p]));
        keep[r][ci] = (mx > 1e-6f) ? 1 : 0;
    }
    __syncthreads();

    if (t < 5) {
        int nd = 0;
        for (int ci = 0; ci < 81; ++ci) {
            dofs[t][ci] = (short)nd;
            nd += keep[t][ci];
        }
        nds[t] = nd;
    }
    __syncthreads();

    if (t < 405) {
        int r = t / 81, ci = t - r * 81;
        if (keep[r][ci]) {
            int d = dofs[r][ci];
            int iy = ci / 9, ix = ci - iy * 9;
            // px-delta * 4 bytes (plane-major tile: px stride = 4 B within a plane)
            uoff[r * UROW + d] = (iy * 24 + (ix - 4)) * 4;
            #pragma unroll
            for (int p = 0; p < 8; ++p)
                wvec[(r * NDCAP + d) * 8 + p] = grid[r][ci][p];
        }
    }
    if (t == 0) {
        int base = 0;
        for (int r = 0; r < 5; ++r) {
            int nd  = nds[r];
            int ndp = (nd + 3) & ~3;          // pad to multiple of 4
            meta[r]      = ndp;
            meta[5 + r]  = base;
            meta[11 + r] = nd;
            base += ndp;
        }
        meta[10] = base;                      // TOTP
    }
}

// ---------------- k1: pack W1eff + W2 into bf16 MFMA fragments ----------------
__global__ void rrf_pack(const float* __restrict__ W1, const float* __restrict__ W2,
                         const int* __restrict__ meta, const float* __restrict__ wvec,
                         unsigned short* __restrict__ w1p, unsigned short* __restrict__ w2p)
{
    int bb = blockIdx.x;
    if (bb < 480) {
        int gid  = bb * 256 + threadIdx.x;    // 122880 = 5*48*2*4*64
        int lane = gid & 63;
        int t    = (gid >> 6) & 3;
        int cc   = (gid >> 8) & 1;
        int rd   = gid >> 9;
        int r = rd / NDCAP, d = rd % NDCAP;
        if (r >= 5 || d >= meta[r]) return;   // meta[r] = padded count
        int TOTP  = meta[10];
        int chunk = cc * TOTP + meta[5 + r] + d;
        unsigned short* dst = w1p + ((size_t)(chunk * 4 + t) * 64 + lane) * 8;
        if (d >= meta[11 + r]) {              // pad chunk: zero A
            short8 z = {0,0,0,0,0,0,0,0};
            *(short8*)dst = z;
            return;
        }
        int n = t * 16 + (lane & 15);
        int cbase = cc * 32 + ((lane >> 4) << 3);
        const float* wv  = wvec + (r * NDCAP + d) * 8;
        const float* w1r = W1 + (size_t)r * 512 * 64;
        short8 o;
        #pragma unroll
        for (int j = 0; j < 8; ++j) {
            int c = cbase + j;
            float acc = 0.f;
            #pragma unroll
            for (int p = 0; p < 8; ++p)
                acc = fmaf(wv[p], w1r[(c * 8 + p) * 64 + n], acc);
            o[j] = (short)f2bf(acc);
        }
        *(short8*)dst = o;
    } else {
        int i = (bb - 480) * 256 + threadIdx.x;
        if (i < 20480) {    // (((r*4+t)*2+kc2)*64+lane)*8+j
            int j    = i & 7;
            int lane = (i >> 3) & 63;
            int kc2  = (i >> 9) & 1;
            int t    = (i >> 10) & 3;
            int r    = i >> 12;
            int n = kc2 * 32 + ((lane >> 4) << 3) + j;
            int m = t * 16 + (lane & 15);
            w2p[i] = f2bf(W2[(r * 64 + n) * 64 + m]);
        }
    }
}

// ---------------- k2: x [b][c][px] fp32 -> xbf [b][px][c] bf16 ----------------
__global__ void rrf_xpose(const float* __restrict__ x, unsigned short* __restrict__ xbf)
{
    __shared__ float tl[64][65];
    int b   = blockIdx.x >> 8;
    int px0 = (blockIdx.x & 255) * 64;
    int tx = threadIdx.x & 63, ty = threadIdx.x >> 6;
    #pragma unroll
    for (int i = 0; i < 16; ++i) {
        int c = i * 4 + ty;
        tl[c][tx] = x[(((size_t)b * 64 + c) << 14) + px0 + tx];
    }
    __syncthreads();
    #pragma unroll
    for (int i = 0; i < 16; ++i) {
        int px = i * 4 + ty;
        xbf[(((size_t)b << 14) + px0 + px) * 64 + tx] = f2bf(tl[tx][px]);
    }
}

// ---------------- k3: main stencil kernel: kc/np/pg retile + plane-major LDS ----------------
// tile planes: plane p = j*4+g, stride 2368 B (592 dw == 16 mod 32 banks -> conflict-free)
#define LDBANK7(AA, BB, D, UU) {                                                          \
    const unsigned short* _p = ap + (size_t)(D) * 2048;                                   \
    AA[0] = *(const short8*)(_p); AA[1] = *(const short8*)(_p + 512);                     \
    const char* _tc = tb_lane + (UU);                                                     \
    _Pragma("unroll")                                                                     \
    for (int _q = 0; _q < 4; ++_q)                                                        \
        _Pragma("unroll")                                                                 \
        for (int _j = 0; _j < 4; ++_j)                                                    \
            BB[_q].d[_j] = *(const unsigned int*)(_tc + _j * 9472 + _q * 96); }

#define MFBANK7(AA, BB) {                                                                 \
    _Pragma("unroll")                                                                     \
    for (int _t = 0; _t < 2; ++_t)                                                        \
        _Pragma("unroll")                                                                 \
        for (int _q = 0; _q < 4; ++_q)                                                    \
            hv[_t][_q] = __builtin_amdgcn_mfma_f32_16x16x32_bf16(AA[_t], BB[_q].s,        \
                                                                 hv[_t][_q], 0, 0, 0); }

__global__ __launch_bounds__(1024, 1)
void rrf_stencil7(const float* __restrict__ x, const unsigned short* __restrict__ xbf,
                  const unsigned short* __restrict__ w1p, const unsigned short* __restrict__ w2p,
                  const int* __restrict__ meta, const int* __restrict__ uoff,
                  const float* __restrict__ b1v, const float* __restrict__ g1v,
                  const float* __restrict__ btv, const float* __restrict__ b2v,
                  float* __restrict__ out)
{
    __shared__ __align__(16) unsigned int tile_u32[18944];   // 2 kc * 16 planes * 592 dw
    __shared__ __align__(16) unsigned char exch[49152];      // [w][lane][48B]: 32B hv-exch + 16B gelu-exch
    __shared__ float wsum[2][16][16][2];                     // [np][row16][col][{s,s2}]
    __shared__ int uo_lds[5 * UROW];
    __shared__ int meta_lds[16];

    const int tid  = threadIdx.x;
    const int w    = tid >> 6;                // 0..15
    const int lane = tid & 63;
    const int col  = lane & 15;
    const int g    = lane >> 4;
    const int kc   = w & 1;                   // channel half
    const int np   = (w >> 1) & 1;            // n half
    const int pg   = w >> 2;                  // row quad (rows 4pg..4pg+3)

    const int bid = blockIdx.x;               // 256 blocks: b(2) | tr(3) | tc(3)
    const int b   = bid >> 6;
    const int r0  = ((bid >> 3) & 7) * 16;
    const int c0  = (bid & 7) * 16;

    if (tid < 5 * UROW) uo_lds[tid] = uoff[tid];
    if (tid >= 5 * UROW && tid < 5 * UROW + 16) meta_lds[tid - 5 * UROW] = meta[tid - 5 * UROW];

    // ---- stage 24x24 halo tile ONCE, plane-major, zero-pad OOB ----
    if (tid < 576) {
        int s = tid;
        int trow = s / 24, tcol = s - trow * 24;
        int row = r0 - 4 + trow, cg = c0 - 4 + tcol;
        bool valid = ((unsigned)row < 128u) && ((unsigned)cg < 128u);
        if (valid) {
            const unsigned short* src =
                xbf + (((size_t)(b << 14)) + row * 128 + cg) * 64;
            #pragma unroll
            for (int h = 0; h < 2; ++h)
                #pragma unroll
                for (int k = 0; k < 4; ++k) {
                    U8 u; u.s = *(const short8*)(src + h * 32 + k * 8);
                    #pragma unroll
                    for (int j = 0; j < 4; ++j)
                        tile_u32[h * 9472 + (j * 4 + k) * 592 + s] = u.d[j];
                }
        } else {
            #pragma unroll
            for (int h = 0; h < 2; ++h)
                #pragma unroll
                for (int k = 0; k < 4; ++k)
                    #pragma unroll
                    for (int j = 0; j < 4; ++j)
                        tile_u32[h * 9472 + (j * 4 + k) * 592 + s] = 0u;
        }
    }
    __syncthreads();

    // per-lane B base: kc half + g plane-group + px(q=0 row) * 4
    const int P004 = ((4 * pg) * 24 + col + 4) * 4;
    const char* tb_lane = (const char*)tile_u32 + kc * 37888 + g * 2368 + P004;

    f32x4 acc2[4];
    #pragma unroll
    for (int t = 0; t < 4; ++t) acc2[t] = f32x4{0.f, 0.f, 0.f, 0.f};

    const int src0 = 32 * (g & 1) + col;
    const int src1 = src0 + 16;
    const bool ghi = (g >> 1) != 0;
    const int R16 = 4 * pg + 2 * kc;          // + i -> global row in tile
    unsigned char* exw = exch + w * 3072 + lane * 48;

    #pragma unroll 1
    for (int r = 0; r < 5; ++r) {
        f32x4 hv[2][4];
        #pragma unroll
        for (int t = 0; t < 2; ++t)
            #pragma unroll
            for (int q = 0; q < 4; ++q) hv[t][q] = f32x4{0.f, 0.f, 0.f, 0.f};

        const int ndp  = __builtin_amdgcn_readfirstlane(meta_lds[r]);
        const int base = __builtin_amdgcn_readfirstlane(meta_lds[5 + r]);
        const int TOTP = __builtin_amdgcn_readfirstlane(meta_lds[10]);
        const int* uo = uo_lds + r * UROW;
        const unsigned short* ap = w1p + (size_t)(kc * TOTP + base) * 2048
                                 + np * 1024 + lane * 8;

        // ---- chunk loop: 2-bank ping-pong, pinned with sched_barrier ----
        short8 A0[2], A1[2];
        U8 B0[4], B1[4];
        LDBANK7(A0, B0, 0, uo[0])
        LDBANK7(A1, B1, 1, uo[1])
        #pragma unroll 1
        for (int d = 0; d < ndp; d += 2) {
            int u2 = uo[d + 2], u3 = uo[d + 3];
            MFBANK7(A0, B0)
            LDBANK7(A0, B0, d + 2, u2)
            __builtin_amdgcn_sched_barrier(0);
            MFBANK7(A1, B1)
            LDBANK7(A1, B1, d + 3, u3)
            __builtin_amdgcn_sched_barrier(0);
        }

        // ---- kc exchange: give 2 rows (bf16), keep 2 rows ----
        {
            unsigned int pk1[8];
            #pragma unroll
            for (int t = 0; t < 2; ++t) {
                f32x4 gv0 = kc ? hv[t][0] : hv[t][2];
                f32x4 gv1 = kc ? hv[t][1] : hv[t][3];
                pk1[t * 4 + 0] = (unsigned int)f2bf(gv0[0]) | ((unsigned int)f2bf(gv0[1]) << 16);
                pk1[t * 4 + 1] = (unsigned int)f2bf(gv0[2]) | ((unsigned int)f2bf(gv0[3]) << 16);
                pk1[t * 4 + 2] = (unsigned int)f2bf(gv1[0]) | ((unsigned int)f2bf(gv1[1]) << 16);
                pk1[t * 4 + 3] = (unsigned int)f2bf(gv1[2]) | ((unsigned int)f2bf(gv1[3]) << 16);
            }
            *(uint4*)(exw)      = make_uint4(pk1[0], pk1[1], pk1[2], pk1[3]);
            *(uint4*)(exw + 16) = make_uint4(pk1[4], pk1[5], pk1[6], pk1[7]);
        }
        __syncthreads();   // BAR1
        unsigned int rr[8];
        {
            const unsigned char* exr = exch + (w ^ 1) * 3072 + lane * 48;
            uint4 ra = *(const uint4*)(exr);
            uint4 rb = *(const uint4*)(exr + 16);
            rr[0] = ra.x; rr[1] = ra.y; rr[2] = ra.z; rr[3] = ra.w;
            rr[4] = rb.x; rr[5] = rb.y; rr[6] = rb.z; rr[7] = rb.w;
        }

        // ---- combine + bias, LN partials over this wave's 32 n ----
        float b1r[2][4], g1r[2][4], btr[2][4];
        #pragma unroll
        for (int t = 0; t < 2; ++t)
            #pragma unroll
            for (int e = 0; e < 4; ++e) {
                int n = np * 32 + t * 16 + g * 4 + e;
                b1r[t][e] = b1v[r * 64 + n];
                g1r[t][e] = g1v[r * 64 + n];
                btr[t][e] = btv[r * 64 + n];
            }
        float hq[2][2][4];   // [i(row)][t][e]
        #pragma unroll
        for (int t = 0; t < 2; ++t) {
            f32x4 k0 = kc ? hv[t][2] : hv[t][0];
            f32x4 k1 = kc ? hv[t][3] : hv[t][1];
            unsigned int a0 = rr[t * 4 + 0], a1 = rr[t * 4 + 1];
            unsigned int a2 = rr[t * 4 + 2], a3 = rr[t * 4 + 3];
            hq[0][t][0] = k0[0] + bflo(a0) + b1r[t][0];
            hq[0][t][1] = k0[1] + bfhi(a0) + b1r[t][1];
            hq[0][t][2] = k0[2] + bflo(a1) + b1r[t][2];
            hq[0][t][3] = k0[3] + bfhi(a1) + b1r[t][3];
            hq[1][t][0] = k1[0] + bflo(a2) + b1r[t][0];
            hq[1][t][1] = k1[1] + bfhi(a2) + b1r[t][1];
            hq[1][t][2] = k1[2] + bflo(a3) + b1r[t][2];
            hq[1][t][3] = k1[3] + bfhi(a3) + b1r[t][3];
        }
        float sA[2], sB[2];
        #pragma unroll
        for (int i = 0; i < 2; ++i) {
            float s = 0.f, s2 = 0.f;
            #pragma unroll
            for (int t = 0; t < 2; ++t)
                #pragma unroll
                for (int e = 0; e < 4; ++e) {
                    float v = hq[i][t][e];
                    s += v;
                    s2 = fmaf(v, v, s2);
                }
            s  += __shfl_xor(s, 16);  s  += __shfl_xor(s, 32);
            s2 += __shfl_xor(s2, 16); s2 += __shfl_xor(s2, 32);
            sA[i] = s; sB[i] = s2;
        }
        if (g == 0) {
            #pragma unroll
            for (int i = 0; i < 2; ++i) {
                wsum[np][R16 + i][col][0] = sA[i];
                wsum[np][R16 + i][col][1] = sB[i];
            }
        }
        __syncthreads();   // BAR2

        // ---- LN finalize + exact GELU, pack bf16 ----
        unsigned int pk[2][2][2];   // [i][t][wd]
        #pragma unroll
        for (int i = 0; i < 2; ++i) {
            float so  = wsum[np ^ 1][R16 + i][col][0];
            float s2o = wsum[np ^ 1][R16 + i][col][1];
            const float mu = (sA[i] + so) * 0.015625f;
            const float ms = (sB[i] + s2o) * 0.015625f;
            const float rs = rsqrtf(ms - mu * mu + 1e-5f);
            #pragma unroll
            for (int t = 0; t < 2; ++t) {
                float ge[4];
                #pragma unroll
                for (int e = 0; e < 4; ++e) {
                    float v = (hq[i][t][e] - mu) * rs * g1r[t][e] + btr[t][e];
                    ge[e] = 0.5f * v * (1.f + erff(v * 0.70710678118654752f));
                }
                pk[i][t][0] = (unsigned int)f2bf(ge[0]) | ((unsigned int)f2bf(ge[1]) << 16);
                pk[i][t][1] = (unsigned int)f2bf(ge[2]) | ((unsigned int)f2bf(ge[3]) << 16);
            }
        }
        // ---- np exchange: give row (np^1), keep row (np) ----
        {
            unsigned int gv0 = np ? pk[0][0][0] : pk[1][0][0];
            unsigned int gv1 = np ? pk[0][0][1] : pk[1][0][1];
            unsigned int gv2 = np ? pk[0][1][0] : pk[1][1][0];
            unsigned int gv3 = np ? pk[0][1][1] : pk[1][1][1];
            *(uint4*)(exw + 32) = make_uint4(gv0, gv1, gv2, gv3);
        }
        __syncthreads();   // BAR3
        unsigned int pkf[2][4];
        {
            uint4 gp = *(const uint4*)(exch + (w ^ 2) * 3072 + lane * 48 + 32);
            unsigned int kp0 = np ? pk[1][0][0] : pk[0][0][0];
            unsigned int kp1 = np ? pk[1][0][1] : pk[0][0][1];
            unsigned int kp2 = np ? pk[1][1][0] : pk[0][1][0];
            unsigned int kp3 = np ? pk[1][1][1] : pk[0][1][1];
            pkf[0][0] = np ? gp.x : kp0;  pkf[1][0] = np ? kp0 : gp.x;
            pkf[0][1] = np ? gp.y : kp1;  pkf[1][1] = np ? kp1 : gp.y;
            pkf[0][2] = np ? gp.z : kp2;  pkf[1][2] = np ? kp2 : gp.z;
            pkf[0][3] = np ? gp.w : kp3;  pkf[1][3] = np ? kp3 : gp.w;
        }

        // ---- GEMM2: wave owns one full row (16 px, 64 n, 64 m) ----
        const unsigned short* a2base = w2p + (size_t)r * 4096 + (size_t)lane * 8;
        #pragma unroll
        for (int kc2 = 0; kc2 < 2; ++kc2) {
            unsigned int d0a = (unsigned int)__shfl((int)pkf[kc2][0], src0);
            unsigned int d0b = (unsigned int)__shfl((int)pkf[kc2][2], src0);
            unsigned int d1a = (unsigned int)__shfl((int)pkf[kc2][1], src0);
            unsigned int d1b = (unsigned int)__shfl((int)pkf[kc2][3], src0);
            unsigned int d2a = (unsigned int)__shfl((int)pkf[kc2][0], src1);
            unsigned int d2b = (unsigned int)__shfl((int)pkf[kc2][2], src1);
            unsigned int d3a = (unsigned int)__shfl((int)pkf[kc2][1], src1);
            unsigned int d3b = (unsigned int)__shfl((int)pkf[kc2][3], src1);
            U8 u;
            u.d[0] = ghi ? d0b : d0a;
            u.d[1] = ghi ? d1b : d1a;
            u.d[2] = ghi ? d2b : d2a;
            u.d[3] = ghi ? d3b : d3a;
            #pragma unroll
            for (int t = 0; t < 4; ++t) {
                short8 a2f = *(const short8*)(a2base + kc2 * 512 + t * 1024);
                acc2[t] = __builtin_amdgcn_mfma_f32_16x16x32_bf16(a2f, u.s, acc2[t], 0, 0, 0);
            }
        }
    }

    // ---- epilogue: + sum_r b2, sigmoid, gate x (wave -> row r0 + 4pg + 2kc + np) ----
    const int Rg = r0 + 4 * pg + 2 * kc + np;
    #pragma unroll
    for (int t = 0; t < 4; ++t) {
        #pragma unroll
        for (int e = 0; e < 4; ++e) {
            int m = t * 16 + g * 4 + e;
            float sb = b2v[m] + b2v[64 + m] + b2v[128 + m] + b2v[192 + m] + b2v[256 + m];
            float a = acc2[t][e] + sb;
            float wts = 1.f / (1.f + expf(-a));
            size_t off = (((size_t)b * 64 + m) << 14) + (size_t)Rg * 128 + (c0 + col);
            out[off] = x[off] * wts;
        }
    }
}

// ================= fallback: round-2 MFMA path (proven) =================
__global__ void rrf_prepack(const float* __restrict__ W1, const float* __restrict__ W2,
                            unsigned short* __restrict__ w1p, unsigned short* __restrict__ w2p)
{
    int i = blockIdx.x * 256 + threadIdx.x;
    if (i < 163840) {
        int jq   = i & 7;
        int lane = (i >> 3) & 63;
        int kc   = (i >> 9) & 15;
        int t    = (i >> 13) & 3;
        int r    = i >> 15;
        int k = kc * 32 + ((lane >> 4) << 3) + jq;
        int n = t * 16 + (lane & 15);
        w1p[i] = f2bf(W1[(r * 512 + k) * 64 + n]);
    }
    if (i < 20480) {
        int jq   = i & 7;
        int lane = (i >> 3) & 63;
        int kc2  = (i >> 9) & 1;
        int t    = (i >> 10) & 3;
        int r    = i >> 12;
        int n = kc2 * 32 + ((lane >> 4) << 3) + jq;
        int m = t * 16 + (lane & 15);
        w2p[i] = f2bf(W2[(r * 64 + n) * 64 + m]);
    }
}

__global__ __launch_bounds__(256, 2)
void rrf_mfma(const float* __restrict__ x,
              const unsigned short* __restrict__ w1p, const unsigned short* __restrict__ w2p,
              const float* __restrict__ b1v, const float* __restrict__ g1v,
              const float* __restrict__ btv, const float* __restrict__ b2v,
              float* __restrict__ out)
{
    __shared__ unsigned short gbuf[4][16][72];

    const int tid  = threadIdx.x;
    const int w    = tid >> 6;
    const int lane = tid & 63;
    const int col  = lane & 15;
    const int g    = lane >> 4;

    const int bid  = blockIdx.x;
    const int b    = bid >> 8;
    const int rem  = bid & 255;
    const int irow = rem >> 1;
    const int j0   = (rem & 1) * 64;
    const int j    = j0 + w * 16 + col;

    const float fi = (float)irow;
    const float fj = (float)j;
    const float* xb = x + ((size_t)b << 20);

    f32x4 acc2[4] = {f32x4{0,0,0,0}, f32x4{0,0,0,0}, f32x4{0,0,0,0}, f32x4{0,0,0,0}};

    #pragma unroll 1
    for (int r = 0; r < 5; ++r) {
        int   o00[8], o01[8], o10[8], o11[8];
        float w00[8], w01[8], w10[8], w11[8];
        const float rf = (float)r;
        #pragma unroll
        for (int p = 0; p < 8; ++p) {
            float ang = (float)p * 0.78539818525314331f;
            float yy = fi + rf * sinf(ang);
            float xx = fj + rf * cosf(ang);
            float y0f = floorf(yy), x0f = floorf(xx);
            float wy = yy - y0f, wx = xx - x0f;
            int y0 = (int)y0f, x0i = (int)x0f;
            int y1 = y0 + 1,   x1  = x0i + 1;
            float m00 = (y0 >= 0 && y0 < Hh && x0i >= 0 && x0i < Ww) ? 1.f : 0.f;
            float m01 = (y0 >= 0 && y0 < Hh && x1  >= 0 && x1  < Ww) ? 1.f : 0.f;
            float m10 = (y1 >= 0 && y1 < Hh && x0i >= 0 && x0i < Ww) ? 1.f : 0.f;
            float m11 = (y1 >= 0 && y1 < Hh && x1  >= 0 && x1  < Ww) ? 1.f : 0.f;
            int y0c = y0 < 0 ? 0 : (y0 > Hh - 1 ? Hh - 1 : y0);
            int y1c = y1 < 0 ? 0 : (y1 > Hh - 1 ? Hh - 1 : y1);
            int x0c = x0i < 0 ? 0 : (x0i > Ww - 1 ? Ww - 1 : x0i);
            int x1c = x1 < 0 ? 0 : (x1 > Ww - 1 ? Ww - 1 : x1);
            w00[p] = (1.f - wy) * (1.f - wx) * m00;
            w01[p] = (1.f - wy) * wx * m01;
            w10[p] = wy * (1.f - wx) * m10;
            w11[p] = wy * wx * m11;
            o00[p] = (y0c * Ww + x0c) * 4;
            o01[p] = (y0c * Ww + x1c) * 4;
            o10[p] = (y1c * Ww + x0c) * 4;
            o11[p] = (y1c * Ww + x1c) * 4;
        }

        f32x4 hv[4] = {f32x4{0,0,0,0}, f32x4{0,0,0,0}, f32x4{0,0,0,0}, f32x4{0,0,0,0}};
        const unsigned short* abase0 = w1p + ((size_t)((r * 64) * 64 + lane)) * 8;
        #pragma unroll 2
        for (int kc = 0; kc < 16; ++kc) {
            const int c = (kc << 2) + g;
            const char* xp = (const char*)(xb + ((size_t)c << 14));
            short8 bfrag;
            #pragma unroll
            for (int p = 0; p < 8; ++p) {
                float v00 = *(const float*)(xp + o00[p]);
                float v01 = *(const float*)(xp + o01[p]);
                float v10 = *(const float*)(xp + o10[p]);
                float v11 = *(const float*)(xp + o11[p]);
                float v = w00[p] * v00;
                v = fmaf(w01[p], v01, v);
                v = fmaf(w10[p], v10, v);
                v = fmaf(w11[p], v11, v);
                bfrag[p] = (short)f2bf(v);
            }
            const unsigned short* ab = abase0 + (size_t)kc * 512;
            #pragma unroll
            for (int t = 0; t < 4; ++t) {
                short8 af = *(const short8*)(ab + (size_t)t * 8192);
                hv[t] = __builtin_amdgcn_mfma_f32_16x16x32_bf16(af, bfrag, hv[t], 0, 0, 0);
            }
        }

        const int nb = g << 2;
        float hq[4][4];
        float s = 0.f;
        #pragma unroll
        for (int t = 0; t < 4; ++t)
            #pragma unroll
            for (int q = 0; q < 4; ++q) {
                float hvq = hv[t][q] + b1v[r * 64 + t * 16 + nb + q];
                hq[t][q] = hvq;
                s += hvq;
            }
        s += __shfl_xor(s, 16);
        s += __shfl_xor(s, 32);
        const float mu = s * 0.015625f;
        float s2 = 0.f;
        #pragma unroll
        for (int t = 0; t < 4; ++t)
            #pragma unroll
            for (int q = 0; q < 4; ++q) {
                float d = hq[t][q] - mu;
                s2 = fmaf(d, d, s2);
            }
        s2 += __shfl_xor(s2, 16);
        s2 += __shfl_xor(s2, 32);
        const float rs = rsqrtf(s2 * 0.015625f + 1e-5f);

        #pragma unroll
        for (int t = 0; t < 4; ++t)
            #pragma unroll
            for (int q = 0; q < 4; ++q) {
                int n = t * 16 + nb + q;
                float v = (hq[t][q] - mu) * rs * g1v[r * 64 + n] + btv[r * 64 + n];
                hq[t][q] = 0.5f * v * (1.f + erff(v * 0.70710678118654752f));
            }
        #pragma unroll
        for (int t = 0; t < 4; ++t) {
            #pragma unroll
            for (int q2 = 0; q2 < 4; q2 += 2) {
                unsigned int u = (unsigned int)f2bf(hq[t][q2])
                               | ((unsigned int)f2bf(hq[t][q2 + 1]) << 16);
                *(unsigned int*)&gbuf[w][col][t * 16 + nb + q2] = u;
            }
        }

        const unsigned short* a2base = w2p + ((size_t)((r * 8) * 64 + lane)) * 8;
        #pragma unroll
        for (int kc2 = 0; kc2 < 2; ++kc2) {
            short8 bf2 = *(const short8*)&gbuf[w][col][kc2 * 32 + g * 8];
            const unsigned short* a2 = a2base + (size_t)kc2 * 512;
            #pragma unroll
            for (int t = 0; t < 4; ++t) {
                short8 a2f = *(const short8*)(a2 + (size_t)t * 1024);
                acc2[t] = __builtin_amdgcn_mfma_f32_16x16x32_bf16(a2f, bf2, acc2[t], 0, 0, 0);
            }
        }
    }

    #pragma unroll
    for (int t = 0; t < 4; ++t) {
        #pragma unroll
        for (int q = 0; q < 4; ++q) {
            int m = t * 16 + (g << 2) + q;
            float sb = b2v[m] + b2v[64 + m] + b2v[128 + m] + b2v[192 + m] + b2v[256 + m];
            float a = acc2[t][q] + sb;
            float wts = 1.f / (1.f + expf(-a));
            size_t off = (((size_t)b * 64 + m) << 14) + ((size_t)irow << 7) + j;
            out[off] = x[off] * wts;
        }
    }
}

extern "C" void kernel_launch(void* const* d_in, const int* in_sizes, int n_in,
                              void* d_out, int out_size, void* d_ws, size_t ws_size,
                              hipStream_t stream)
{
    const float* x  = (const float*)d_in[0];
    const float* W1 = (const float*)d_in[1];
    const float* b1 = (const float*)d_in[2];
    const float* g1 = (const float*)d_in[3];
    const float* bt = (const float*)d_in[4];
    const float* W2 = (const float*)d_in[5];
    const float* b2 = (const float*)d_in[6];
    float* outp = (float*)d_out;
    char* ws = (char*)d_ws;

    if (ws_size >= WS_NEED) {
        unsigned short* xbf = (unsigned short*)(ws + XBF_OFF);
        unsigned short* w1p = (unsigned short*)(ws + W1P_OFF);
        unsigned short* w2p = (unsigned short*)(ws + W2P_OFF);
        int*   meta  = (int*)(ws + META_OFF);
        int*   uoffp = (int*)(ws + UOFF_OFF);
        float* wvec  = (float*)(ws + WVEC_OFF);

        rrf_xpose<<<dim3(1024), dim3(256), 0, stream>>>(x, xbf);
        rrf_table<<<dim3(1), dim3(512), 0, stream>>>(meta, uoffp, wvec);
        rrf_pack<<<dim3(564), dim3(256), 0, stream>>>(W1, W2, meta, wvec, w1p, w2p);
        rrf_stencil7<<<dim3(256), dim3(1024), 0, stream>>>(x, xbf, w1p, w2p, meta, uoffp,
                                                           b1, g1, bt, b2, outp);
    } else {
        unsigned short* w1p = (unsigned short*)d_ws;
        unsigned short* w2p = w1p + 163840;
        rrf_prepack<<<dim3(640), dim3(256), 0, stream>>>(W1, W2, w1p, w2p);
        rrf_mfma<<<dim3(1024), dim3(256), 0, stream>>>(x, w1p, w2p, b1, g1, bt, b2, outp);
    }
}

// Round 11
// 89.760 us; speedup vs baseline: 1.6920x; 1.6920x over previous
//
#include <hip/hip_runtime.h>
#include <math.h>

namespace {
constexpr int Hh = 128, Ww = 128;
constexpr int NDCAP = 48;     // max stencil offsets per radius
constexpr int UROW  = 56;     // uoff row stride in ints

using short8 = __attribute__((ext_vector_type(8))) short;
using f32x4  = __attribute__((ext_vector_type(4))) float;

__device__ __forceinline__ unsigned short f2bf(float f) {
    union { float f; unsigned int u; } v; v.f = f;
    unsigned int u = v.u;
    unsigned int r = (u + 0x7FFFu + ((u >> 16) & 1u)) >> 16;   // RNE
    return (unsigned short)r;
}

union U8 { unsigned int d[4]; short8 s; };

// workspace layout (bytes)
constexpr size_t XBF_OFF  = 0;                                  // 4*16384*64 bf16 = 8388608
constexpr size_t W1P_OFF  = 8388608;                            // 484 chunks * 4096 B
constexpr size_t W2P_OFF  = W1P_OFF + (size_t)484 * 4096;       // 40960 B
constexpr size_t META_OFF = W2P_OFF + 40960;                    // 64 B (16 ints)
constexpr size_t UOFF_OFF = META_OFF + 64;                      // 5*56*4 = 1120 -> 1152
constexpr size_t WVEC_OFF = UOFF_OFF + 1152;                    // 5*48*8*4 = 7680
constexpr size_t WS_NEED  = WVEC_OFF + 7680;
}

// ---------------- k0: stencil table builder (parallel, deterministic) ----------------
__global__ void rrf_table(int* __restrict__ meta, int* __restrict__ uoff,
                          float* __restrict__ wvec)
{
    __shared__ float grid[5][81][8];
    __shared__ unsigned char keep[5][81];
    __shared__ short dofs[5][81];
    __shared__ int nds[5];

    const int t = threadIdx.x;                // 512 threads
    for (int i = t; i < 5 * 81 * 8; i += 512) ((float*)grid)[i] = 0.f;
    for (int i = t; i < 5 * UROW; i += 512) uoff[i] = 0;
    __syncthreads();

    if (t < 40) {                             // one thread per (r,p) tap set
        int r = t >> 3, p = t & 7;
        float ang = (float)p * 0.78539818525314331f;     // f32(2pi)/8
        float si = (float)sin((double)ang);
        float co = (float)cos((double)ang);
        float di = (float)r * si;
        float dj = (float)r * co;
        float y0f = floorf(di), x0f = floorf(dj);
        float wy = di - y0f, wx = dj - x0f;
        int y0 = (int)y0f, x0 = (int)x0f;
        float tw[4] = {(1.f - wy) * (1.f - wx), (1.f - wy) * wx,
                       wy * (1.f - wx), wy * wx};
        int ty[4] = {y0, y0, y0 + 1, y0 + 1};
        int tx[4] = {x0, x0 + 1, x0, x0 + 1};
        #pragma unroll
        for (int q = 0; q < 4; ++q) {
            if (fabsf(tw[q]) < 1e-6f) continue;
            grid[r][(ty[q] + 4) * 9 + (tx[q] + 4)][p] = tw[q];
        }
    }
    __syncthreads();

    if (t < 405) {
        int r = t / 81, ci = t - r * 81;
        float mx = 0.f;
        #pragma unroll
        for (int p = 0; p < 8; ++p) mx = fmaxf(mx, fabsf(grid[r][ci][p]));
        keep[r][ci] = (mx > 1e-6f) ? 1 : 0;
    }
    __syncthreads();

    if (t < 5) {
        int nd = 0;
        for (int ci = 0; ci < 81; ++ci) {
            dofs[t][ci] = (short)nd;
            nd += keep[t][ci];
        }
        nds[t] = nd;
    }
    __syncthreads();

    if (t < 405) {
        int r = t / 81, ci = t - r * 81;
        if (keep[r][ci]) {
            int d = dofs[r][ci];
            int iy = ci / 9, ix = ci - iy * 9;
            // LDS byte offset delta within the halo tile (stride 80 B/px, 24 px/row)
            uoff[r * UROW + d] = (iy * 24 + (ix - 4)) * 80;
            #pragma unroll
            for (int p = 0; p < 8; ++p)
                wvec[(r * NDCAP + d) * 8 + p] = grid[r][ci][p];
        }
    }
    if (t == 0) {
        int base = 0;
        for (int r = 0; r < 5; ++r) {
            int nd  = nds[r];
            int ndp = (nd + 3) & ~3;          // pad to multiple of 4 (4-bank pipeline)
            meta[r]      = ndp;
            meta[5 + r]  = base;
            meta[11 + r] = nd;
            base += ndp;
        }
        meta[10] = base;                      // TOTP
    }
}

// ---------------- k1: pack W1eff + W2 into bf16 MFMA fragments ----------------
__global__ void rrf_pack(const float* __restrict__ W1, const float* __restrict__ W2,
                         const int* __restrict__ meta, const float* __restrict__ wvec,
                         unsigned short* __restrict__ w1p, unsigned short* __restrict__ w2p)
{
    int bb = blockIdx.x;
    if (bb < 480) {
        int gid  = bb * 256 + threadIdx.x;    // 122880 = 5*48*2*4*64
        int lane = gid & 63;
        int t    = (gid >> 6) & 3;
        int cc   = (gid >> 8) & 1;
        int rd   = gid >> 9;
        int r = rd / NDCAP, d = rd % NDCAP;
        if (r >= 5 || d >= meta[r]) return;   // meta[r] = padded count
        int TOTP  = meta[10];
        int chunk = cc * TOTP + meta[5 + r] + d;
        unsigned short* dst = w1p + ((size_t)(chunk * 4 + t) * 64 + lane) * 8;
        if (d >= meta[11 + r]) {              // pad chunk: zero A
            short8 z = {0,0,0,0,0,0,0,0};
            *(short8*)dst = z;
            return;
        }
        int n = t * 16 + (lane & 15);
        int cbase = cc * 32 + ((lane >> 4) << 3);
        const float* wv  = wvec + (r * NDCAP + d) * 8;
        const float* w1r = W1 + (size_t)r * 512 * 64;
        short8 o;
        #pragma unroll
        for (int j = 0; j < 8; ++j) {
            int c = cbase + j;
            float acc = 0.f;
            #pragma unroll
            for (int p = 0; p < 8; ++p)
                acc = fmaf(wv[p], w1r[(c * 8 + p) * 64 + n], acc);
            o[j] = (short)f2bf(acc);
        }
        *(short8*)dst = o;
    } else {
        int i = (bb - 480) * 256 + threadIdx.x;
        if (i < 20480) {    // (((r*4+t)*2+kc2)*64+lane)*8+j
            int j    = i & 7;
            int lane = (i >> 3) & 63;
            int kc2  = (i >> 9) & 1;
            int t    = (i >> 10) & 3;
            int r    = i >> 12;
            int n = kc2 * 32 + ((lane >> 4) << 3) + j;
            int m = t * 16 + (lane & 15);
            w2p[i] = f2bf(W2[(r * 64 + n) * 64 + m]);
        }
    }
}

// ---------------- k2: x [b][c][px] fp32 -> xbf [b][px][c] bf16 ----------------
__global__ void rrf_xpose(const float* __restrict__ x, unsigned short* __restrict__ xbf)
{
    __shared__ float tl[64][65];
    int b   = blockIdx.x >> 8;
    int px0 = (blockIdx.x & 255) * 64;
    int tx = threadIdx.x & 63, ty = threadIdx.x >> 6;
    #pragma unroll
    for (int i = 0; i < 16; ++i) {
        int c = i * 4 + ty;
        tl[c][tx] = x[(((size_t)b * 64 + c) << 14) + px0 + tx];
    }
    __syncthreads();
    #pragma unroll
    for (int i = 0; i < 16; ++i) {
        int px = i * 4 + ty;
        xbf[(((size_t)b << 14) + px0 + px) * 64 + tx] = f2bf(tl[tx][px]);
    }
}

// ---------------- k3: main stencil: 8 waves, 8x16 px tile, 2 blocks/CU ----------------
#define LDA6(K, CI) { const unsigned short* _q = ap + (size_t)(CI) * 2048 + tsel + (lane << 3); \
    A##K[0] = *(const short8*)(_q); A##K[1] = *(const short8*)(_q + 512); }

#define LDB6(K, U) {                                                                      \
    B##K[0] = *(const short8*)(tb + ((U) + lbq0));                                        \
    B##K[1] = *(const short8*)(tb + ((U) + lbq1)); }

#define MF6(K) {                                                                          \
    hv[0][0] = __builtin_amdgcn_mfma_f32_16x16x32_bf16(A##K[0], B##K[0], hv[0][0], 0, 0, 0); \
    hv[0][1] = __builtin_amdgcn_mfma_f32_16x16x32_bf16(A##K[0], B##K[1], hv[0][1], 0, 0, 0); \
    hv[1][0] = __builtin_amdgcn_mfma_f32_16x16x32_bf16(A##K[1], B##K[0], hv[1][0], 0, 0, 0); \
    hv[1][1] = __builtin_amdgcn_mfma_f32_16x16x32_bf16(A##K[1], B##K[1], hv[1][1], 0, 0, 0); }

__global__ __launch_bounds__(512, 4)
void rrf_stencil8(const float* __restrict__ x, const unsigned short* __restrict__ xbf,
                  const unsigned short* __restrict__ w1p, const unsigned short* __restrict__ w2p,
                  const int* __restrict__ meta, const int* __restrict__ uoff,
                  const float* __restrict__ b1v, const float* __restrict__ g1v,
                  const float* __restrict__ btv, const float* __restrict__ b2v,
                  float* __restrict__ out)
{
    __shared__ __align__(16) unsigned short tile[2][15360];  // 2 halves x 384 px x 80 B
    __shared__ __align__(16) uint4 exch[512];                // 16 B per thread
    __shared__ float wsum[2][8][16][2];                      // [tp][row][col][{s,s2}]
    __shared__ int uo_lds[5 * UROW];
    __shared__ int meta_lds[16];

    const int tid  = threadIdx.x;
    const int w    = tid >> 6;                // 0..7
    const int lane = tid & 63;
    const int col  = lane & 15;
    const int g    = lane >> 4;
    const int tp   = w & 1;                   // n-half owner
    const int pg   = w >> 1;                  // row-pair owner (rows 2pg, 2pg+1)
    const int tsel = tp * 1024;               // ushort offset of this wave's A slice

    const int bid = blockIdx.x;               // 512 blocks: b(2) | tr(4) | tc(3)
    const int b   = bid >> 7;
    const int r0  = ((bid >> 3) & 15) * 8;
    const int c0  = (bid & 7) * 16;

    // per-wave B row bases (within one 30720-B half, stride 80 B/px, 24 px halo cols)
    const int lbq0 = ((2 * pg + 0) * 24 + col + 4) * 80 + g * 16;
    const int lbq1 = ((2 * pg + 1) * 24 + col + 4) * 80 + g * 16;

    if (tid < 5 * UROW) uo_lds[tid] = uoff[tid];
    if (tid >= 5 * UROW && tid < 5 * UROW + 16) meta_lds[tid - 5 * UROW] = meta[tid - 5 * UROW];

    // ---- stage the 16x24 halo tile ONCE (both channel halves), zero-pad OOB ----
    if (tid < 384) {
        int s = tid;
        int trow = s / 24, tcol = s - trow * 24;
        int row = r0 - 4 + trow, cg = c0 - 4 + tcol;
        bool valid = ((unsigned)row < 128u) && ((unsigned)cg < 128u);
        unsigned short* d0 = &tile[0][s * 40];
        unsigned short* d1 = &tile[1][s * 40];
        if (valid) {
            const unsigned short* src =
                xbf + (((size_t)(b << 14)) + row * 128 + cg) * 64;
            #pragma unroll
            for (int k = 0; k < 4; ++k) {
                *(short8*)(d0 + k * 8) = *(const short8*)(src + k * 8);
                *(short8*)(d1 + k * 8) = *(const short8*)(src + 32 + k * 8);
            }
        } else {
            short8 z = {0, 0, 0, 0, 0, 0, 0, 0};
            #pragma unroll
            for (int k = 0; k < 4; ++k) {
                *(short8*)(d0 + k * 8) = z;
                *(short8*)(d1 + k * 8) = z;
            }
        }
    }
    __syncthreads();

    f32x4 acc2[4];                             // GEMM2 accum: wave owns row 2pg+tp, all 64 m
    #pragma unroll
    for (int t = 0; t < 4; ++t) acc2[t] = f32x4{0.f, 0.f, 0.f, 0.f};

    const int src0 = 32 * (g & 1) + col;       // shfl sources for GEMM2 B-frag exchange
    const int src1 = src0 + 16;
    const bool ghi = (g >> 1) != 0;
    const int R8 = 2 * pg;

    #pragma unroll 1
    for (int r = 0; r < 5; ++r) {
        f32x4 hv[2][2];                        // [t][q(row i)]
        #pragma unroll
        for (int t = 0; t < 2; ++t)
            #pragma unroll
            for (int q = 0; q < 2; ++q) hv[t][q] = f32x4{0.f, 0.f, 0.f, 0.f};

        const int ndp  = __builtin_amdgcn_readfirstlane(meta_lds[r]);      // mult of 4
        const int base = __builtin_amdgcn_readfirstlane(meta_lds[5 + r]);
        const int TOTP = __builtin_amdgcn_readfirstlane(meta_lds[10]);
        const int* uo = uo_lds + r * UROW;

        #pragma unroll 1
        for (int cc = 0; cc < 2; ++cc) {
            const unsigned short* ap = w1p + (size_t)(cc * TOTP + base) * 2048;
            const char* tb = (const char*)(&tile[cc][0]);

            // 4-bank register pipeline, prefetch distance 3 banks
            short8 A0[2], A1[2], A2[2], A3[2];
            short8 B0[2], B1[2], B2[2], B3[2];
            LDA6(0, 0) LDB6(0, uo[0])
            LDA6(1, 1) LDB6(1, uo[1])
            LDA6(2, 2) LDB6(2, uo[2])
            LDA6(3, 3) LDB6(3, uo[3])
            int u0 = uo[4], u1 = uo[5], u2 = uo[6], u3 = uo[7];
            #pragma unroll 1
            for (int d = 0; d < ndp; d += 4) {
                MF6(0) LDA6(0, d + 4) LDB6(0, u0)
                MF6(1) LDA6(1, d + 5) LDB6(1, u1)
                MF6(2) LDA6(2, d + 6) LDB6(2, u2)
                MF6(3) LDA6(3, d + 7) LDB6(3, u3)
                u0 = uo[d + 8];  u1 = uo[d + 9];
                u2 = uo[d + 10]; u3 = uo[d + 11];
            }
        }

        // ---- bias + LayerNorm partials (wave owns 32 of 64 n for rows 2pg,2pg+1) ----
        float b1r[2][4], g1r[2][4], btr[2][4];
        #pragma unroll
        for (int t = 0; t < 2; ++t)
            #pragma unroll
            for (int e = 0; e < 4; ++e) {
                int n = (2 * tp + t) * 16 + g * 4 + e;
                b1r[t][e] = b1v[r * 64 + n];
                g1r[t][e] = g1v[r * 64 + n];
                btr[t][e] = btv[r * 64 + n];
            }

        float hq[2][2][4];                     // [t][q(row i)][e]
        float sA[2], sB[2];
        #pragma unroll
        for (int q = 0; q < 2; ++q) {
            float s = 0.f, s2 = 0.f;
            #pragma unroll
            for (int t = 0; t < 2; ++t)
                #pragma unroll
                for (int e = 0; e < 4; ++e) {
                    float v = hv[t][q][e] + b1r[t][e];
                    hq[t][q][e] = v;
                    s += v;
                    s2 = fmaf(v, v, s2);
                }
            s  += __shfl_xor(s, 16);  s  += __shfl_xor(s, 32);
            s2 += __shfl_xor(s2, 16); s2 += __shfl_xor(s2, 32);
            sA[q] = s; sB[q] = s2;
        }
        if (g == 0) {
            #pragma unroll
            for (int q = 0; q < 2; ++q) {
                wsum[tp][R8 + q][col][0] = sA[q];
                wsum[tp][R8 + q][col][1] = sB[q];
            }
        }
        __syncthreads();   // BAR1: LN partials visible

        // ---- LN finalize + exact GELU, pack bf16: pk[row i][t][wd] ----
        unsigned int pk[2][2][2];
        #pragma unroll
        for (int q = 0; q < 2; ++q) {
            float so  = wsum[tp ^ 1][R8 + q][col][0];
            float s2o = wsum[tp ^ 1][R8 + q][col][1];
            const float mu = (sA[q] + so) * 0.015625f;
            const float ms = (sB[q] + s2o) * 0.015625f;
            const float rs = rsqrtf(ms - mu * mu + 1e-5f);
            #pragma unroll
            for (int t = 0; t < 2; ++t) {
                float ge[4];
                #pragma unroll
                for (int e = 0; e < 4; ++e) {
                    float v = (hq[t][q][e] - mu) * rs * g1r[t][e] + btr[t][e];
                    ge[e] = 0.5f * v * (1.f + erff(v * 0.70710678118654752f));
                }
                pk[q][t][0] = (unsigned int)f2bf(ge[0]) | ((unsigned int)f2bf(ge[1]) << 16);
                pk[q][t][1] = (unsigned int)f2bf(ge[2]) | ((unsigned int)f2bf(ge[3]) << 16);
            }
        }

        // ---- tp exchange: give row (tp^1), keep row tp -> full-n row ownership ----
        {
            int ig = tp ^ 1;
            exch[tid] = make_uint4(pk[ig][0][0], pk[ig][0][1], pk[ig][1][0], pk[ig][1][1]);
        }
        __syncthreads();   // BAR2: exchange visible
        unsigned int pkf[4][2];                // [n>>4][wd] for row 2pg+tp, full n
        {
            uint4 po = exch[(w ^ 1) * 64 + lane];
            pkf[2 * tp + 0][0] = pk[tp][0][0];  pkf[2 * tp + 0][1] = pk[tp][0][1];
            pkf[2 * tp + 1][0] = pk[tp][1][0];  pkf[2 * tp + 1][1] = pk[tp][1][1];
            int ot = 2 * (tp ^ 1);
            pkf[ot + 0][0] = po.x;  pkf[ot + 0][1] = po.y;
            pkf[ot + 1][0] = po.z;  pkf[ot + 1][1] = po.w;
        }

        // ---- GEMM2: B-frag via in-register lane exchange (r5-proven mapping) ----
        const unsigned short* a2base = w2p + (size_t)r * 4096 + (size_t)lane * 8;
        #pragma unroll
        for (int kc2 = 0; kc2 < 2; ++kc2) {
            unsigned int d0a = (unsigned int)__shfl((int)pkf[kc2 * 2][0],     src0);
            unsigned int d0b = (unsigned int)__shfl((int)pkf[kc2 * 2 + 1][0], src0);
            unsigned int d1a = (unsigned int)__shfl((int)pkf[kc2 * 2][1],     src0);
            unsigned int d1b = (unsigned int)__shfl((int)pkf[kc2 * 2 + 1][1], src0);
            unsigned int d2a = (unsigned int)__shfl((int)pkf[kc2 * 2][0],     src1);
            unsigned int d2b = (unsigned int)__shfl((int)pkf[kc2 * 2 + 1][0], src1);
            unsigned int d3a = (unsigned int)__shfl((int)pkf[kc2 * 2][1],     src1);
            unsigned int d3b = (unsigned int)__shfl((int)pkf[kc2 * 2 + 1][1], src1);
            U8 u;
            u.d[0] = ghi ? d0b : d0a;
            u.d[1] = ghi ? d1b : d1a;
            u.d[2] = ghi ? d2b : d2a;
            u.d[3] = ghi ? d3b : d3a;
            #pragma unroll
            for (int t = 0; t < 4; ++t) {
                short8 a2f = *(const short8*)(a2base + kc2 * 512 + t * 1024);
                acc2[t] = __builtin_amdgcn_mfma_f32_16x16x32_bf16(a2f, u.s, acc2[t], 0, 0, 0);
            }
        }
    }

    // ---- epilogue: + sum_r b2, sigmoid, gate x (wave -> image row r0 + 2pg + tp) ----
    const int Rg = r0 + 2 * pg + tp;
    #pragma unroll
    for (int t = 0; t < 4; ++t) {
        #pragma unroll
        for (int e = 0; e < 4; ++e) {
            int m = t * 16 + g * 4 + e;
            float sb = b2v[m] + b2v[64 + m] + b2v[128 + m] + b2v[192 + m] + b2v[256 + m];
            float a = acc2[t][e] + sb;
            float wts = 1.f / (1.f + expf(-a));
            size_t off = (((size_t)b * 64 + m) << 14) + (size_t)Rg * 128 + (c0 + col);
            out[off] = x[off] * wts;
        }
    }
}

// ================= fallback: round-2 MFMA path (proven) =================
__global__ void rrf_prepack(const float* __restrict__ W1, const float* __restrict__ W2,
                            unsigned short* __restrict__ w1p, unsigned short* __restrict__ w2p)
{
    int i = blockIdx.x * 256 + threadIdx.x;
    if (i < 163840) {
        int jq   = i & 7;
        int lane = (i >> 3) & 63;
        int kc   = (i >> 9) & 15;
        int t    = (i >> 13) & 3;
        int r    = i >> 15;
        int k = kc * 32 + ((lane >> 4) << 3) + jq;
        int n = t * 16 + (lane & 15);
        w1p[i] = f2bf(W1[(r * 512 + k) * 64 + n]);
    }
    if (i < 20480) {
        int jq   = i & 7;
        int lane = (i >> 3) & 63;
        int kc2  = (i >> 9) & 1;
        int t    = (i >> 10) & 3;
        int r    = i >> 12;
        int n = kc2 * 32 + ((lane >> 4) << 3) + jq;
        int m = t * 16 + (lane & 15);
        w2p[i] = f2bf(W2[(r * 64 + n) * 64 + m]);
    }
}

__global__ __launch_bounds__(256, 2)
void rrf_mfma(const float* __restrict__ x,
              const unsigned short* __restrict__ w1p, const unsigned short* __restrict__ w2p,
              const float* __restrict__ b1v, const float* __restrict__ g1v,
              const float* __restrict__ btv, const float* __restrict__ b2v,
              float* __restrict__ out)
{
    __shared__ unsigned short gbuf[4][16][72];

    const int tid  = threadIdx.x;
    const int w    = tid >> 6;
    const int lane = tid & 63;
    const int col  = lane & 15;
    const int g    = lane >> 4;

    const int bid  = blockIdx.x;
    const int b    = bid >> 8;
    const int rem  = bid & 255;
    const int irow = rem >> 1;
    const int j0   = (rem & 1) * 64;
    const int j    = j0 + w * 16 + col;

    const float fi = (float)irow;
    const float fj = (float)j;
    const float* xb = x + ((size_t)b << 20);

    f32x4 acc2[4] = {f32x4{0,0,0,0}, f32x4{0,0,0,0}, f32x4{0,0,0,0}, f32x4{0,0,0,0}};

    #pragma unroll 1
    for (int r = 0; r < 5; ++r) {
        int   o00[8], o01[8], o10[8], o11[8];
        float w00[8], w01[8], w10[8], w11[8];
        const float rf = (float)r;
        #pragma unroll
        for (int p = 0; p < 8; ++p) {
            float ang = (float)p * 0.78539818525314331f;
            float yy = fi + rf * sinf(ang);
            float xx = fj + rf * cosf(ang);
            float y0f = floorf(yy), x0f = floorf(xx);
            float wy = yy - y0f, wx = xx - x0f;
            int y0 = (int)y0f, x0i = (int)x0f;
            int y1 = y0 + 1,   x1  = x0i + 1;
            float m00 = (y0 >= 0 && y0 < Hh && x0i >= 0 && x0i < Ww) ? 1.f : 0.f;
            float m01 = (y0 >= 0 && y0 < Hh && x1  >= 0 && x1  < Ww) ? 1.f : 0.f;
            float m10 = (y1 >= 0 && y1 < Hh && x0i >= 0 && x0i < Ww) ? 1.f : 0.f;
            float m11 = (y1 >= 0 && y1 < Hh && x1  >= 0 && x1  < Ww) ? 1.f : 0.f;
            int y0c = y0 < 0 ? 0 : (y0 > Hh - 1 ? Hh - 1 : y0);
            int y1c = y1 < 0 ? 0 : (y1 > Hh - 1 ? Hh - 1 : y1);
            int x0c = x0i < 0 ? 0 : (x0i > Ww - 1 ? Ww - 1 : x0i);
            int x1c = x1 < 0 ? 0 : (x1 > Ww - 1 ? Ww - 1 : x1);
            w00[p] = (1.f - wy) * (1.f - wx) * m00;
            w01[p] = (1.f - wy) * wx * m01;
            w10[p] = wy * (1.f - wx) * m10;
            w11[p] = wy * wx * m11;
            o00[p] = (y0c * Ww + x0c) * 4;
            o01[p] = (y0c * Ww + x1c) * 4;
            o10[p] = (y1c * Ww + x0c) * 4;
            o11[p] = (y1c * Ww + x1c) * 4;
        }

        f32x4 hv[4] = {f32x4{0,0,0,0}, f32x4{0,0,0,0}, f32x4{0,0,0,0}, f32x4{0,0,0,0}};
        const unsigned short* abase0 = w1p + ((size_t)((r * 64) * 64 + lane)) * 8;
        #pragma unroll 2
        for (int kc = 0; kc < 16; ++kc) {
            const int c = (kc << 2) + g;
            const char* xp = (const char*)(xb + ((size_t)c << 14));
            short8 bfrag;
            #pragma unroll
            for (int p = 0; p < 8; ++p) {
                float v00 = *(const float*)(xp + o00[p]);
                float v01 = *(const float*)(xp + o01[p]);
                float v10 = *(const float*)(xp + o10[p]);
                float v11 = *(const float*)(xp + o11[p]);
                float v = w00[p] * v00;
                v = fmaf(w01[p], v01, v);
                v = fmaf(w10[p], v10, v);
                v = fmaf(w11[p], v11, v);
                bfrag[p] = (short)f2bf(v);
            }
            const unsigned short* ab = abase0 + (size_t)kc * 512;
            #pragma unroll
            for (int t = 0; t < 4; ++t) {
                short8 af = *(const short8*)(ab + (size_t)t * 8192);
                hv[t] = __builtin_amdgcn_mfma_f32_16x16x32_bf16(af, bfrag, hv[t], 0, 0, 0);
            }
        }

        const int nb = g << 2;
        float hq[4][4];
        float s = 0.f;
        #pragma unroll
        for (int t = 0; t < 4; ++t)
            #pragma unroll
            for (int q = 0; q < 4; ++q) {
                float hvq = hv[t][q] + b1v[r * 64 + t * 16 + nb + q];
                hq[t][q] = hvq;
                s += hvq;
            }
        s += __shfl_xor(s, 16);
        s += __shfl_xor(s, 32);
        const float mu = s * 0.015625f;
        float s2 = 0.f;
        #pragma unroll
        for (int t = 0; t < 4; ++t)
            #pragma unroll
            for (int q = 0; q < 4; ++q) {
                float d = hq[t][q] - mu;
                s2 = fmaf(d, d, s2);
            }
        s2 += __shfl_xor(s2, 16);
        s2 += __shfl_xor(s2, 32);
        const float rs = rsqrtf(s2 * 0.015625f + 1e-5f);

        #pragma unroll
        for (int t = 0; t < 4; ++t)
            #pragma unroll
            for (int q = 0; q < 4; ++q) {
                int n = t * 16 + nb + q;
                float v = (hq[t][q] - mu) * rs * g1v[r * 64 + n] + btv[r * 64 + n];
                hq[t][q] = 0.5f * v * (1.f + erff(v * 0.70710678118654752f));
            }
        #pragma unroll
        for (int t = 0; t < 4; ++t) {
            #pragma unroll
            for (int q2 = 0; q2 < 4; q2 += 2) {
                unsigned int u = (unsigned int)f2bf(hq[t][q2])
                               | ((unsigned int)f2bf(hq[t][q2 + 1]) << 16);
                *(unsigned int*)&gbuf[w][col][t * 16 + nb + q2] = u;
            }
        }

        const unsigned short* a2base = w2p + ((size_t)((r * 8) * 64 + lane)) * 8;
        #pragma unroll
        for (int kc2 = 0; kc2 < 2; ++kc2) {
            short8 bf2 = *(const short8*)&gbuf[w][col][kc2 * 32 + g * 8];
            const unsigned short* a2 = a2base + (size_t)kc2 * 512;
            #pragma unroll
            for (int t = 0; t < 4; ++t) {
                short8 a2f = *(const short8*)(a2 + (size_t)t * 1024);
                acc2[t] = __builtin_amdgcn_mfma_f32_16x16x32_bf16(a2f, bf2, acc2[t], 0, 0, 0);
            }
        }
    }

    #pragma unroll
    for (int t = 0; t < 4; ++t) {
        #pragma unroll
        for (int q = 0; q < 4; ++q) {
            int m = t * 16 + (g << 2) + q;
            float sb = b2v[m] + b2v[64 + m] + b2v[128 + m] + b2v[192 + m] + b2v[256 + m];
            float a = acc2[t][q] + sb;
            float wts = 1.f / (1.f + expf(-a));
            size_t off = (((size_t)b * 64 + m) << 14) + ((size_t)irow << 7) + j;
            out[off] = x[off] * wts;
        }
    }
}

extern "C" void kernel_launch(void* const* d_in, const int* in_sizes, int n_in,
                              void* d_out, int out_size, void* d_ws, size_t ws_size,
                              hipStream_t stream)
{
    const float* x  = (const float*)d_in[0];
    const float* W1 = (const float*)d_in[1];
    const float* b1 = (const float*)d_in[2];
    const float* g1 = (const float*)d_in[3];
    const float* bt = (const float*)d_in[4];
    const float* W2 = (const float*)d_in[5];
    const float* b2 = (const float*)d_in[6];
    float* outp = (float*)d_out;
    char* ws = (char*)d_ws;

    if (ws_size >= WS_NEED) {
        unsigned short* xbf = (unsigned short*)(ws + XBF_OFF);
        unsigned short* w1p = (unsigned short*)(ws + W1P_OFF);
        unsigned short* w2p = (unsigned short*)(ws + W2P_OFF);
        int*   meta  = (int*)(ws + META_OFF);
        int*   uoffp = (int*)(ws + UOFF_OFF);
        float* wvec  = (float*)(ws + WVEC_OFF);

        rrf_xpose<<<dim3(1024), dim3(256), 0, stream>>>(x, xbf);
        rrf_table<<<dim3(1), dim3(512), 0, stream>>>(meta, uoffp, wvec);
        rrf_pack<<<dim3(564), dim3(256), 0, stream>>>(W1, W2, meta, wvec, w1p, w2p);
        rrf_stencil8<<<dim3(512), dim3(512), 0, stream>>>(x, xbf, w1p, w2p, meta, uoffp,
                                                          b1, g1, bt, b2, outp);
    } else {
        unsigned short* w1p = (unsigned short*)d_ws;
        unsigned short* w2p = w1p + 163840;
        rrf_prepack<<<dim3(640), dim3(256), 0, stream>>>(W1, W2, w1p, w2p);
        rrf_mfma<<<dim3(1024), dim3(256), 0, stream>>>(x, w1p, w2p, b1, g1, bt, b2, outp);
    }
}